// Round 4
// baseline (102.137 us; speedup 1.0000x reference)
//
#include <hip/hip_runtime.h>
#include <hip/hip_bf16.h>

// Chamfer distance between two (1,16384,3) fp32 clouds.
// Inner score: t = x.y - |y|^2/2 (maximized over y) => d2min = |x|^2 - 2*max_t.
// Core: 3 v_pk_fma_f32 + 1 v_max3_f32 per (1 x-point x 2 y-points) = 2 instr/pair.
// XPT=16 amortizes each broadcast ds_read_b128 over 4x more math than R3,
// flipping the kernel from LDS-pipe-bound (~41us demand) to VALU-bound (~14us).

constexpr int P      = 16384;
constexpr int BLK    = 256;
constexpr int XPT    = 16;              // x points per thread (96 VGPR packed)
constexpr int XCHUNK = BLK * XPT;       // 4096 -> 4 x-chunks
constexpr int YSPLIT = 64;              // y segments -> grid 4*64*2 = 512 blocks
constexpr int YSEG   = P / YSPLIT;      // 256 y per segment (one LDS stage)
constexpr int NGRP   = YSEG / 2;        // 128 y-pair groups of 8 floats

typedef float v2f __attribute__((ext_vector_type(2)));

static __device__ inline v2f pk_fma(v2f a, v2f b, v2f c) {
    v2f d;
    asm("v_pk_fma_f32 %0, %1, %2, %3" : "=v"(d) : "v"(a), "v"(b), "v"(c));
    return d;
}
static __device__ inline float max3(float a, float b, float c) {
    float d;
    asm("v_max3_f32 %0, %1, %2, %3" : "=v"(d) : "v"(a), "v"(b), "v"(c));
    return d;
}

// ---------------- main: per-(dir, y-segment) partial max of t ----------------
__global__ __launch_bounds__(BLK, 2) void chamfer_main(
    const float* __restrict__ pc1, const float* __restrict__ pc2,
    float* __restrict__ partial,    // [2][YSPLIT][P] of max_t
    float* __restrict__ out)        // zeroed here (reduce atomicAdds later)
{
    if (blockIdx.x == 0 && blockIdx.y == 0 && blockIdx.z == 0 && threadIdx.x == 0)
        out[0] = 0.0f;

    const int dir = blockIdx.z;
    const float* xs = dir ? pc2 : pc1;
    const float* ys = dir ? pc1 : pc2;

    // ---- stage y segment into LDS, interleaved pair-groups:
    //      group g = { x0,x1, y0,y1, z0,z1, w0,w1 }  (w = -|y|^2/2)
    //      built via lane-pair shuffle so each thread writes ONE float4 (b128,
    //      conflict-free) instead of 4 scattered floats (8-way conflicts in R3).
    __shared__ __align__(16) float yt[NGRP * 8];
    {
        const int j = threadIdx.x;              // one y point per thread (YSEG==BLK)
        const int q = blockIdx.y * YSEG + j;
        const float a = ys[3 * q], b = ys[3 * q + 1], c = ys[3 * q + 2];
        const float w = -0.5f * fmaf(a, a, fmaf(b, b, c * c));
        const float a2 = __shfl_xor(a, 1, 64);  // partner lane's values
        const float b2 = __shfl_xor(b, 1, 64);
        const float c2 = __shfl_xor(c, 1, 64);
        const float w2 = __shfl_xor(w, 1, 64);
        // even lane j=2g writes {x0,x1,y0,y1}; odd lane j=2g+1 writes {z0,z1,w0,w1}
        const float4 v = (j & 1) ? make_float4(c2, c, w2, w)
                                 : make_float4(a, a2, b, b2);
        ((float4*)yt)[j] = v;
    }

    // ---- per-thread x points, splat into v2f for packed math ----
    const int p0 = blockIdx.x * XCHUNK + threadIdx.x;
    v2f xs0[XPT], xs1[XPT], xs2[XPT];
    float acc[XPT];
    #pragma unroll
    for (int k = 0; k < XPT; ++k) {
        const int p = p0 + k * BLK;
        const float a = xs[3 * p], b = xs[3 * p + 1], c = xs[3 * p + 2];
        xs0[k] = (v2f){a, a};
        xs1[k] = (v2f){b, b};
        xs2[k] = (v2f){c, c};
        acc[k] = -3.0e38f;
    }
    __syncthreads();

    // ---- inner loop: one y-pair group per iter = 2 broadcast ds_read_b128,
    //      then 16 x-points x (3 v_pk_fma_f32 + 1 v_max3_f32) = 64 VALU instrs.
    const float4* gptr = (const float4*)yt;
    #pragma unroll 2
    for (int g = 0; g < NGRP; ++g) {
        const float4 A = gptr[2 * g];           // x0,x1,y0,y1
        const float4 B = gptr[2 * g + 1];       // z0,z1,w0,w1
        const v2f y0 = {A.x, A.y};
        const v2f y1 = {A.z, A.w};
        const v2f y2 = {B.x, B.y};
        const v2f yw = {B.z, B.w};
        #pragma unroll
        for (int k = 0; k < XPT; ++k) {
            v2f t = pk_fma(xs0[k], y0, yw);
            t = pk_fma(xs1[k], y1, t);
            t = pk_fma(xs2[k], y2, t);
            acc[k] = max3(acc[k], t.x, t.y);
        }
    }

    float* pout = partial + ((size_t)dir * YSPLIT + blockIdx.y) * P;
    #pragma unroll
    for (int k = 0; k < XPT; ++k) pout[p0 + k * BLK] = acc[k];
}

// ---------------- reduce: max over segments, d2, threshold, mean, atomic ----
__global__ __launch_bounds__(BLK) void chamfer_reduce(
    const float* __restrict__ partial,
    const float* __restrict__ pc1, const float* __restrict__ pc2,
    float* __restrict__ out)
{
    const int gid = blockIdx.x * BLK + threadIdx.x;   // 0 .. 2P-1
    const int dir = (gid >= P) ? 1 : 0;
    const int p = gid & (P - 1);
    const float* xsrc = dir ? pc2 : pc1;
    const float* base = partial + (size_t)dir * YSPLIT * P + p;

    float M = base[0];
    #pragma unroll
    for (int s = 1; s < YSPLIT; ++s) M = fmaxf(M, base[(size_t)s * P]);

    const float a = xsrc[3 * p], b = xsrc[3 * p + 1], c = xsrc[3 * p + 2];
    const float xx = fmaf(a, a, fmaf(b, b, c * c));
    float d2 = fmaf(-2.0f, M, xx);                    // |x|^2 - 2*max_t
    if (d2 >= 2.0f) d2 = 0.0f;                        // DIST_THD mask
    float v = d2 * (1.0f / (float)P);                 // mean over points; N=1

    #pragma unroll
    for (int off = 32; off > 0; off >>= 1) v += __shfl_down(v, off, 64);

    __shared__ float wsum[BLK / 64];
    const int lane = threadIdx.x & 63;
    const int wv = threadIdx.x >> 6;
    if (lane == 0) wsum[wv] = v;
    __syncthreads();
    if (threadIdx.x == 0) {
        float s = wsum[0];
        #pragma unroll
        for (int w = 1; w < BLK / 64; ++w) s += wsum[w];
        atomicAdd(out, s);
    }
}

extern "C" void kernel_launch(void* const* d_in, const int* in_sizes, int n_in,
                              void* d_out, int out_size, void* d_ws, size_t ws_size,
                              hipStream_t stream) {
    const float* pc1 = (const float*)d_in[0];
    const float* pc2 = (const float*)d_in[1];
    float* out = (float*)d_out;
    float* partial = (float*)d_ws;                     // 2*YSPLIT*P floats = 8 MB

    dim3 grid(P / XCHUNK, YSPLIT, 2);                  // 4 x 64 x 2 = 512 blocks
    chamfer_main<<<grid, BLK, 0, stream>>>(pc1, pc2, partial, out);
    chamfer_reduce<<<(2 * P) / BLK, BLK, 0, stream>>>(partial, pc1, pc2, out);
}